// Round 12
// baseline (127.970 us; speedup 1.0000x reference)
//
#include <hip/hip_runtime.h>
#include <hip/hip_bf16.h>
#include <stdint.h>

#define IN_F   2048
#define OUT_F  2048
#define NTOK   8192
#define KAUG   2176   // 2048 + E*R
#define RANKE  128    // E*R
#define SCALING 2.0f
#define NT64   34     // KAUG / 64
#define NITER  17     // NT64 / 2

typedef float  f32x4 __attribute__((ext_vector_type(4)));
typedef __bf16 bf16x8 __attribute__((ext_vector_type(8)));

#define GLOAD(g, l) __builtin_amdgcn_global_load_lds(                                   \
    (const __attribute__((address_space(1))) unsigned int*)(g),                          \
    (__attribute__((address_space(3))) unsigned int*)(l), 16, 0, 0)
#define PIN()    asm volatile("" ::: "memory")
#define BAR()    __builtin_amdgcn_s_barrier()
#define WAITL()  asm volatile("s_waitcnt lgkmcnt(0)" ::: "memory")
#define WAITV0() asm volatile("s_waitcnt vmcnt(0)" ::: "memory")
#define WAITV4() asm volatile("s_waitcnt vmcnt(4)" ::: "memory")
#define SB0()    __builtin_amdgcn_sched_barrier(0)

__device__ __forceinline__ unsigned short f2b(float f) {
  union { float f; unsigned u; } v; v.f = f;
  return (unsigned short)((v.u + 0x7FFFu + ((v.u >> 16) & 1u)) >> 16);
}

__device__ __forceinline__ uint4 pack8(float4 a, float4 b) {
  uint4 p;
  p.x = f2b(a.x) | ((unsigned)f2b(a.y) << 16);
  p.y = f2b(a.z) | ((unsigned)f2b(a.w) << 16);
  p.z = f2b(b.x) | ((unsigned)f2b(b.y) << 16);
  p.w = f2b(b.z) | ((unsigned)f2b(b.w) << 16);
  return p;
}

__device__ __forceinline__ uint2 pack4(float4 a) {
  uint2 p;
  p.x = f2b(a.x) | ((unsigned)f2b(a.y) << 16);
  p.y = f2b(a.z) | ((unsigned)f2b(a.w) << 16);
  return p;
}

// ---------------------------------------------------------------------------
// ONE pre-kernel: 256 blocks x 32 tokens.
//  ph1+2: x -> bf16 (global + swizzled LDS) + f32 router -> gates in LDS
//  wt:    8 B'-rows per block (weight + lora_B), old role verbatim
//  ph3:   V[32][128] = gate * (x_lds . Acat^T) via MFMA, lora_A staged
//         f32->bf16 per K-tile (reg-prefetched), write A'[:,2048:2176]
// ---------------------------------------------------------------------------
__global__ __launch_bounds__(256)
void k_prep(const float* __restrict__ x, const float* __restrict__ rw,
            const float* __restrict__ wt, const float* __restrict__ lb,
            const float* __restrict__ la,
            unsigned short* __restrict__ Ap, unsigned short* __restrict__ Bp) {
  __shared__ alignas(16) unsigned short xs[32 * 2048];   // 128KB, chunk^(row&7) swizzle
  __shared__ alignas(16) unsigned short as_[128 * 64];   // 16KB Acat tile, swizzled
  __shared__ float ws[32][8];                            // gates

  const int pb = blockIdx.x;
  const int t = threadIdx.x;
  const int w = t >> 6, l = t & 63;
  const int n0 = pb * 32;

  // ---- phase 1+2: wave w handles tokens [w*8, w*8+8) as 4 pairs
  for (int p = 0; p < 4; ++p) {
    const int tk0 = w * 8 + p * 2;
    float4 xr[2][8];
    #pragma unroll
    for (int ti = 0; ti < 2; ++ti) {
      const int row = tk0 + ti;
      const float4* xp = (const float4*)(x + (size_t)(n0 + row) * IN_F);
      uint2* dst = (uint2*)(Ap + (size_t)(n0 + row) * KAUG);
      #pragma unroll
      for (int j = 0; j < 8; ++j) {
        int idx = j * 64 + l;
        float4 a = xp[idx];
        xr[ti][j] = a;
        uint2 pk = pack4(a);
        dst[idx] = pk;
        *(uint2*)((char*)xs + row * 4096 + (((idx >> 1) ^ (row & 7)) << 4) + (idx & 1) * 8) = pk;
      }
    }
    float acc[2][8];
    #pragma unroll
    for (int ti = 0; ti < 2; ++ti)
      #pragma unroll
      for (int e = 0; e < 8; ++e) acc[ti][e] = 0.f;
    #pragma unroll
    for (int e = 0; e < 8; ++e) {
      const float4* wp = (const float4*)(rw + (size_t)e * IN_F);
      #pragma unroll
      for (int j = 0; j < 8; ++j) {
        float4 b = wp[j * 64 + l];
        #pragma unroll
        for (int ti = 0; ti < 2; ++ti)
          acc[ti][e] += xr[ti][j].x * b.x + xr[ti][j].y * b.y +
                        xr[ti][j].z * b.z + xr[ti][j].w * b.w;
      }
    }
    #pragma unroll
    for (int ti = 0; ti < 2; ++ti)
      #pragma unroll
      for (int e = 0; e < 8; ++e) {
        #pragma unroll
        for (int msk = 1; msk <= 32; msk <<= 1) acc[ti][e] += __shfl_xor(acc[ti][e], msk);
      }
    #pragma unroll
    for (int ti = 0; ti < 2; ++ti) {
      float m = acc[ti][0];
      #pragma unroll
      for (int e = 1; e < 8; ++e) m = fmaxf(m, acc[ti][e]);
      float ex[8], dn = 0.f;
      #pragma unroll
      for (int e = 0; e < 8; ++e) { ex[e] = expf(acc[ti][e] - m); dn += ex[e]; }
      float inv = 1.f / dn;
      float v1 = -1.f; int i1 = 0;
      #pragma unroll
      for (int e = 0; e < 8; ++e) {
        float pr = ex[e] * inv;
        if (pr > v1) { v1 = pr; i1 = e; }
      }
      float v2 = -1.f; int i2 = 0;
      #pragma unroll
      for (int e = 0; e < 8; ++e) {
        float pr = ex[e] * inv;
        if (e != i1 && pr > v2) { v2 = pr; i2 = e; }
      }
      if ((l >> 3) == ti) {
        int e = l & 7;
        float wsum = v1 + v2;
        float wv = (e == i1) ? (v1 / wsum) : ((e == i2) ? (v2 / wsum) : 0.f);
        ws[tk0 + ti][e] = wv * SCALING;
      }
    }
  }

  // ---- B' build: 8 rows per block (old wt role, looped)
  #pragma unroll
  for (int i = 0; i < 8; ++i) {
    const int o = pb * 8 + i;
    const float4* src = (const float4*)(wt + (size_t)o * IN_F + t * 8);
    *(uint4*)(Bp + (size_t)o * KAUG + t * 8) = pack8(src[0], src[1]);
    if (t < RANKE) {
      float v = lb[((size_t)(t >> 4) * OUT_F + o) * 16 + (t & 15)];
      Bp[(size_t)o * KAUG + IN_F + t] = f2b(v);
    }
  }

  // ---- phase 3: V-MFMA. 4 waves, wave w covers cols [w*32, w*32+32).
  f32x4 vacc[2][2];
  #pragma unroll
  for (int i = 0; i < 2; ++i)
    #pragma unroll
    for (int j = 0; j < 2; ++j) vacc[i][j] = f32x4{0.f, 0.f, 0.f, 0.f};
  const int lr = l & 15, lq = l >> 4;

  float4 abuf[8];
  #pragma unroll
  for (int i = 0; i < 8; ++i) {
    int fi = i * 256 + t, r = fi >> 4, kq = fi & 15;
    abuf[i] = ((const float4*)la)[r * 512 + kq];
  }
  for (int kt = 0; kt < 32; ++kt) {
    #pragma unroll
    for (int i = 0; i < 8; ++i) {
      int fi = i * 256 + t, r = fi >> 4, kq = fi & 15;
      *(uint2*)((char*)as_ + r * 128 + (((kq >> 1) ^ (r & 7)) << 4) + (kq & 1) * 8) = pack4(abuf[i]);
    }
    if (kt + 1 < 32) {
      #pragma unroll
      for (int i = 0; i < 8; ++i) {
        int fi = i * 256 + t, r = fi >> 4, kq = fi & 15;
        abuf[i] = ((const float4*)la)[r * 512 + (kt + 1) * 16 + kq];
      }
    }
    __syncthreads();
    bf16x8 xf[2][2], bf[2][2];
    #pragma unroll
    for (int mi = 0; mi < 2; ++mi)
      #pragma unroll
      for (int ks = 0; ks < 2; ++ks) {
        int row = lr + mi * 16;
        int ch = kt * 8 + ks * 4 + lq;
        xf[mi][ks] = *(const bf16x8*)((char*)xs + row * 4096 + ((ch ^ (row & 7)) << 4));
      }
    #pragma unroll
    for (int ni = 0; ni < 2; ++ni)
      #pragma unroll
      for (int ks = 0; ks < 2; ++ks) {
        int r = w * 32 + ni * 16 + lr;
        int ch = ks * 4 + lq;
        bf[ni][ks] = *(const bf16x8*)((char*)as_ + r * 128 + ((ch ^ (r & 7)) << 4));
      }
    #pragma unroll
    for (int mi = 0; mi < 2; ++mi)
      #pragma unroll
      for (int ni = 0; ni < 2; ++ni)
        #pragma unroll
        for (int ks = 0; ks < 2; ++ks)
          vacc[mi][ni] = __builtin_amdgcn_mfma_f32_16x16x32_bf16(xf[mi][ks], bf[ni][ks], vacc[mi][ni], 0, 0, 0);
    __syncthreads();
  }
  // epilogue: gate-scale, write V into A'[:, 2048:2176]
  #pragma unroll
  for (int mi = 0; mi < 2; ++mi)
    #pragma unroll
    for (int ni = 0; ni < 2; ++ni)
      #pragma unroll
      for (int j = 0; j < 4; ++j) {
        int row = mi * 16 + lq * 4 + j;
        int col = w * 32 + ni * 16 + lr;
        float g = ws[row][w * 2 + ni];
        Ap[(size_t)(n0 + row) * KAUG + IN_F + col] = f2b(vacc[mi][ni][j] * g);
      }
}

// ---------------------------------------------------------------------------
// Main GEMM: 8-phase / 2-K-tile schedule, single barrier per phase
// (R11-proven, byte-identical).
// ---------------------------------------------------------------------------
__global__ __launch_bounds__(512, 2)
void k_main(const unsigned short* __restrict__ A, const unsigned short* __restrict__ B,
            float* __restrict__ out) {
  __shared__ alignas(16) unsigned short LDS[65536];   // A: [0,32768) B: [32768,65536) shorts

  const int tid = threadIdx.x;
  const int id = blockIdx.x;
  const int wg = (id & 7) * 32 + (id >> 3);   // XCD-contiguous
  const int bn = wg >> 5, bm = wg & 31;
  const int w = tid >> 6, l = tid & 63;
  const int wr = w >> 2, wc = w & 3;
  const int lr = l & 15, lq = l >> 4, lx = l & 7;

  const unsigned short* Ablk = A + (size_t)bm * 256 * KAUG;
  const unsigned short* Bblk = B + (size_t)bn * 256 * KAUG;

  const size_t gofs0 = (size_t)(tid >> 3) * KAUG + (size_t)(((tid & 7) ^ ((tid >> 3) & 7)) * 8);
  const size_t gofs1 = (size_t)((tid + 512) >> 3) * KAUG +
                       (size_t)((((tid + 512) & 7) ^ (((tid + 512) >> 3) & 7)) * 8);
  unsigned short* const ldsW = LDS + w * 512;   // wave-uniform dest base

  const int arow = wr * 128 + lr, brow = wc * 64 + lr;
  const int sl0 = (lq ^ lx) * 8, sl1 = ((4 + lq) ^ lx) * 8;

  f32x4 acc[8][4];
  #pragma unroll
  for (int i = 0; i < 8; ++i)
    #pragma unroll
    for (int j = 0; j < 4; ++j) acc[i][j] = f32x4{0.f, 0.f, 0.f, 0.f};
  bf16x8 aF[4][2], bF[4][2];

  auto stage = [&](int isB, int half, int kt) {
    if (kt >= NT64) return;
    const unsigned short* g = (isB ? Bblk : Ablk) + (size_t)(half * 128) * KAUG + (size_t)kt * 64;
    unsigned short* ld = ldsW + isB * 32768 + (kt & 1) * 16384 + half * 8192;
    GLOAD(g + gofs0, ld);
    GLOAD(g + gofs1, ld + 4096);
  };

#define QUAD(MQ, NQ)                                                                     \
  do {                                                                                   \
    _Pragma("unroll") for (int mi_ = 0; mi_ < 4; ++mi_)                                  \
    _Pragma("unroll") for (int ni_ = 0; ni_ < 2; ++ni_)                                  \
    _Pragma("unroll") for (int ks_ = 0; ks_ < 2; ++ks_)                                  \
      acc[(MQ)*4 + mi_][(NQ)*2 + ni_] = __builtin_amdgcn_mfma_f32_16x16x32_bf16(         \
          aF[mi_][ks_], bF[(NQ)*2 + ni_][ks_], acc[(MQ)*4 + mi_][(NQ)*2 + ni_],          \
          0, 0, 0);                                                                      \
  } while (0)

  // prologue: tile0 full + B-halves of tile1; vmcnt(4) -> tile0 resident
  stage(1, 0, 0); stage(1, 1, 0); stage(0, 0, 0); stage(0, 1, 0);
  stage(1, 0, 1); stage(1, 1, 1);
  WAITV4(); PIN(); BAR();

  for (int i = 0; i < NITER; ++i) {
    const int k1 = 2 * i + 1;
    const int a0 = arow * 64,   b0 = 32768 + brow * 64;    // even tile -> buf0
    const int a1 = a0 + 16384,  b1 = b0 + 16384;           // odd tile  -> buf1

    // ---- ph1
    #pragma unroll
    for (int mi = 0; mi < 4; ++mi) {
      aF[mi][0] = *(const bf16x8*)(LDS + a0 + mi * 1024 + sl0);
      aF[mi][1] = *(const bf16x8*)(LDS + a0 + mi * 1024 + sl1);
    }
    #pragma unroll
    for (int ni = 0; ni < 2; ++ni) {
      bF[ni][0] = *(const bf16x8*)(LDS + b0 + ni * 1024 + sl0);
      bF[ni][1] = *(const bf16x8*)(LDS + b0 + ni * 1024 + sl1);
    }
    stage(0, 0, k1);
    PIN(); WAITL(); SB0();
    __builtin_amdgcn_s_setprio(1); QUAD(0, 0); __builtin_amdgcn_s_setprio(0);
    PIN(); BAR();
    // ---- ph2
    #pragma unroll
    for (int ni = 2; ni < 4; ++ni) {
      bF[ni][0] = *(const bf16x8*)(LDS + b0 + ni * 1024 + sl0);
      bF[ni][1] = *(const bf16x8*)(LDS + b0 + ni * 1024 + sl1);
    }
    stage(0, 1, k1);
    PIN(); WAITL(); SB0();
    __builtin_amdgcn_s_setprio(1); QUAD(0, 1); __builtin_amdgcn_s_setprio(0);
    PIN(); BAR();
    // ---- ph3
    #pragma unroll
    for (int mi = 0; mi < 4; ++mi) {
      aF[mi][0] = *(const bf16x8*)(LDS + a0 + (mi + 4) * 1024 + sl0);
      aF[mi][1] = *(const bf16x8*)(LDS + a0 + (mi + 4) * 1024 + sl1);
    }
    stage(1, 0, k1 + 1);
    PIN(); WAITL(); SB0();
    __builtin_amdgcn_s_setprio(1); QUAD(1, 1); __builtin_amdgcn_s_setprio(0);
    PIN(); BAR();
    // ---- ph4
    stage(1, 1, k1 + 1);
    PIN();
    __builtin_amdgcn_s_setprio(1); QUAD(1, 0); __builtin_amdgcn_s_setprio(0);
    PIN();
    if (i == NITER - 1) { WAITV0(); } else { WAITV4(); }
    PIN(); BAR();

    // ---- ph5
    #pragma unroll
    for (int mi = 0; mi < 4; ++mi) {
      aF[mi][0] = *(const bf16x8*)(LDS + a1 + mi * 1024 + sl0);
      aF[mi][1] = *(const bf16x8*)(LDS + a1 + mi * 1024 + sl1);
    }
    #pragma unroll
    for (int ni = 0; ni < 2; ++ni) {
      bF[ni][0] = *(const bf16x8*)(LDS + b1 + ni * 1024 + sl0);
      bF[ni][1] = *(const bf16x8*)(LDS + b1 + ni * 1024 + sl1);
    }
    stage(0, 0, k1 + 1);
    PIN(); WAITL(); SB0();
    __builtin_amdgcn_s_setprio(1); QUAD(0, 0); __builtin_amdgcn_s_setprio(0);
    PIN(); BAR();
    // ---- ph6
    #pragma unroll
    for (int ni = 2; ni < 4; ++ni) {
      bF[ni][0] = *(const bf16x8*)(LDS + b1 + ni * 1024 + sl0);
      bF[ni][1] = *(const bf16x8*)(LDS + b1 + ni * 1024 + sl1);
    }
    stage(0, 1, k1 + 1);
    PIN(); WAITL(); SB0();
    __builtin_amdgcn_s_setprio(1); QUAD(0, 1); __builtin_amdgcn_s_setprio(0);
    PIN(); BAR();
    // ---- ph7
    #pragma unroll
    for (int mi = 0; mi < 4; ++mi) {
      aF[mi][0] = *(const bf16x8*)(LDS + a1 + (mi + 4) * 1024 + sl0);
      aF[mi][1] = *(const bf16x8*)(LDS + a1 + (mi + 4) * 1024 + sl1);
    }
    stage(1, 0, k1 + 2);
    PIN(); WAITL(); SB0();
    __builtin_amdgcn_s_setprio(1); QUAD(1, 1); __builtin_amdgcn_s_setprio(0);
    PIN(); BAR();
    // ---- ph8
    stage(1, 1, k1 + 2);
    PIN();
    __builtin_amdgcn_s_setprio(1); QUAD(1, 0); __builtin_amdgcn_s_setprio(0);
    PIN();
    if (i == NITER - 1) { WAITV0(); } else { WAITV4(); }
    PIN(); BAR();
  }
#undef QUAD

  #pragma unroll
  for (int mi = 0; mi < 8; ++mi)
    #pragma unroll
    for (int ni = 0; ni < 4; ++ni)
      #pragma unroll
      for (int j = 0; j < 4; ++j) {
        int row = bm * 256 + wr * 128 + mi * 16 + lq * 4 + j;
        int col = bn * 256 + wc * 64 + ni * 16 + lr;
        out[(size_t)row * OUT_F + col] = acc[mi][ni][j];
      }
}

extern "C" void kernel_launch(void* const* d_in, const int* in_sizes, int n_in,
                              void* d_out, int out_size, void* d_ws, size_t ws_size,
                              hipStream_t stream) {
  const float* x  = (const float*)d_in[0];
  const float* wt = (const float*)d_in[1];
  const float* la = (const float*)d_in[2];
  const float* lb = (const float*)d_in[3];
  const float* rw = (const float*)d_in[4];
  float* out = (float*)d_out;
  char* ws = (char*)d_ws;

  unsigned short* Ap  = (unsigned short*)ws;                 // bf16 [8192][2176]
  unsigned short* Bp  = (unsigned short*)(ws + 35651584);    // bf16 [2048][2176]

  k_prep<<<256, 256, 0, stream>>>(x, rw, wt, lb, la, Ap, Bp);
  k_main<<<256, 512, 0, stream>>>(Ap, Bp, out);
}

// Round 13
// 123.362 us; speedup vs baseline: 1.0373x; 1.0373x over previous
//
#include <hip/hip_runtime.h>
#include <hip/hip_bf16.h>
#include <stdint.h>

#define IN_F   2048
#define OUT_F  2048
#define NTOK   8192
#define KAUG   2176   // 2048 + E*R
#define RANKE  128    // E*R
#define SCALING 2.0f
#define NT64   34     // KAUG / 64
#define NITER  17     // NT64 / 2

typedef float  f32x4 __attribute__((ext_vector_type(4)));
typedef __bf16 bf16x8 __attribute__((ext_vector_type(8)));

#define GLOAD(g, l) __builtin_amdgcn_global_load_lds(                                   \
    (const __attribute__((address_space(1))) unsigned int*)(g),                          \
    (__attribute__((address_space(3))) unsigned int*)(l), 16, 0, 0)
#define PIN()    asm volatile("" ::: "memory")
#define BAR()    __builtin_amdgcn_s_barrier()
#define WAITL()  asm volatile("s_waitcnt lgkmcnt(0)" ::: "memory")
#define WAITV0() asm volatile("s_waitcnt vmcnt(0)" ::: "memory")
#define WAITV4() asm volatile("s_waitcnt vmcnt(4)" ::: "memory")
#define WAITV10() asm volatile("s_waitcnt vmcnt(10)" ::: "memory")
#define SB0()    __builtin_amdgcn_sched_barrier(0)

__device__ __forceinline__ unsigned short f2b(float f) {
  union { float f; unsigned u; } v; v.f = f;
  return (unsigned short)((v.u + 0x7FFFu + ((v.u >> 16) & 1u)) >> 16);
}

__device__ __forceinline__ uint4 pack8(float4 a, float4 b) {
  uint4 p;
  p.x = f2b(a.x) | ((unsigned)f2b(a.y) << 16);
  p.y = f2b(a.z) | ((unsigned)f2b(a.w) << 16);
  p.z = f2b(b.x) | ((unsigned)f2b(b.y) << 16);
  p.w = f2b(b.z) | ((unsigned)f2b(b.w) << 16);
  return p;
}

__device__ __forceinline__ uint2 pack4(float4 a) {
  uint2 p;
  p.x = f2b(a.x) | ((unsigned)f2b(a.y) << 16);
  p.y = f2b(a.z) | ((unsigned)f2b(a.w) << 16);
  return p;
}

// ---------------------------------------------------------------------------
// Merged pre-pass (R10/R11-proven, unchanged). Role by blockIdx:
//   [0,1024):     prep — 2 tokens/wave, lane l holds float4 idx j*64+l
//                 (coalesced); convert+store bf16 AND router dots; butterfly;
//                 scalar softmax/top2. x read ONCE.
//   [1024,3072):  build B' row (weight + lora_B)
//   [3072,3080):  convert lora_A -> Acat bf16
// ---------------------------------------------------------------------------
__global__ __launch_bounds__(256)
void k_pre(const float* __restrict__ x, const float* __restrict__ rw,
           const float* __restrict__ wt, const float* __restrict__ lb,
           const float* __restrict__ la,
           unsigned short* __restrict__ Ap, float* __restrict__ wsc,
           unsigned short* __restrict__ Bp, unsigned short* __restrict__ Ac) {
  const int bid = blockIdx.x;
  const int t = threadIdx.x;

  if (bid >= 3072) {          // ---- convert lora_A: 8 blocks x 16 rows
    const int r0 = (bid - 3072) * 16;
    #pragma unroll
    for (int j = 0; j < 16; ++j) {
      int ch = j * 256 + t;
      int row = r0 + (ch >> 8), col8 = ch & 255;
      const float4* src = (const float4*)(la + (size_t)row * IN_F + col8 * 8);
      *(uint4*)(Ac + (size_t)row * IN_F + col8 * 8) = pack8(src[0], src[1]);
    }
    return;
  }
  if (bid >= 1024) {          // ---- build B' row o
    const int o = bid - 1024;
    const int c = t * 8;
    const float4* src = (const float4*)(wt + (size_t)o * IN_F + c);
    *(uint4*)(Bp + (size_t)o * KAUG + c) = pack8(src[0], src[1]);
    if (t < RANKE) {
      float v = lb[((size_t)(t >> 4) * OUT_F + o) * 16 + (t & 15)];
      Bp[(size_t)o * KAUG + IN_F + t] = f2b(v);
    }
    return;
  }

  // ---- prep role: 8 tokens per block, 2 per wave
  const int w = t >> 6, l = t & 63;
  const int n0 = bid * 8 + w * 2;

  float4 xr[2][8];
  #pragma unroll
  for (int ti = 0; ti < 2; ++ti) {
    const float4* xp = (const float4*)(x + (size_t)(n0 + ti) * IN_F);
    uint2* dst = (uint2*)(Ap + (size_t)(n0 + ti) * KAUG);
    #pragma unroll
    for (int j = 0; j < 8; ++j) {
      float4 a = xp[j * 64 + l];
      xr[ti][j] = a;
      dst[j * 64 + l] = pack4(a);
    }
  }
  float acc[2][8];
  #pragma unroll
  for (int ti = 0; ti < 2; ++ti)
    #pragma unroll
    for (int e = 0; e < 8; ++e) acc[ti][e] = 0.f;
  #pragma unroll
  for (int e = 0; e < 8; ++e) {
    const float4* wp = (const float4*)(rw + (size_t)e * IN_F);
    #pragma unroll
    for (int j = 0; j < 8; ++j) {
      float4 b = wp[j * 64 + l];
      #pragma unroll
      for (int ti = 0; ti < 2; ++ti)
        acc[ti][e] += xr[ti][j].x * b.x + xr[ti][j].y * b.y +
                      xr[ti][j].z * b.z + xr[ti][j].w * b.w;
    }
  }
  #pragma unroll
  for (int ti = 0; ti < 2; ++ti)
    #pragma unroll
    for (int e = 0; e < 8; ++e) {
      #pragma unroll
      for (int msk = 1; msk <= 32; msk <<= 1) acc[ti][e] += __shfl_xor(acc[ti][e], msk);
    }
  #pragma unroll
  for (int ti = 0; ti < 2; ++ti) {
    float m = acc[ti][0];
    #pragma unroll
    for (int e = 1; e < 8; ++e) m = fmaxf(m, acc[ti][e]);
    float ex[8], dn = 0.f;
    #pragma unroll
    for (int e = 0; e < 8; ++e) { ex[e] = expf(acc[ti][e] - m); dn += ex[e]; }
    float inv = 1.f / dn;
    float v1 = -1.f; int i1 = 0;
    #pragma unroll
    for (int e = 0; e < 8; ++e) {
      float p = ex[e] * inv;
      if (p > v1) { v1 = p; i1 = e; }
    }
    float v2 = -1.f; int i2 = 0;
    #pragma unroll
    for (int e = 0; e < 8; ++e) {
      float p = ex[e] * inv;
      if (e != i1 && p > v2) { v2 = p; i2 = e; }
    }
    if ((l >> 3) == ti) {
      int e = l & 7;
      float wsum = v1 + v2;
      float wv = (e == i1) ? (v1 / wsum) : ((e == i2) ? (v2 / wsum) : 0.f);
      wsc[(size_t)(n0 + ti) * 8 + e] = wv * SCALING;
    }
  }
}

// ---------------------------------------------------------------------------
// LoRA-A GEMM v2: V = gate-scaled (x_bf16 . Acat^T). 32x128 tile, 256 blocks,
// 4 waves. Ring-3 LDS with K-tile=128 (LA [32][128], LB [128][128], 120KB):
// 16 iterations (was 32), 10 uniform loads/thread/stg, counted vmcnt(10)
// keeps 1 stg (one full K-tile pair) in flight — same proven 2-ahead ring-3
// pattern, half the serial barrier/wait chain. chunk^(row&7) swizzle applied
// on the global source (linear LDS dest), inverted on read.
// ---------------------------------------------------------------------------
__global__ __launch_bounds__(256)
void k_lora(const unsigned short* __restrict__ Ap, const unsigned short* __restrict__ Ac,
            const float* __restrict__ wsc, unsigned short* __restrict__ Vout) {
  __shared__ alignas(16) unsigned short LA[3 * 4096];    // 3 x [32][128]  (24KB)
  __shared__ alignas(16) unsigned short LB[3 * 16384];   // 3 x [128][128] (96KB)
  const int t = threadIdx.x, bm = blockIdx.x;
  const int w = t >> 6, l = t & 63;
  const int lr = l & 15, lq = l >> 4;
  const unsigned short* Ablk = Ap + (size_t)bm * 32 * KAUG;

  f32x4 acc[2][2];
  #pragma unroll
  for (int i = 0; i < 2; ++i)
    #pragma unroll
    for (int j = 0; j < 2; ++j) acc[i][j] = f32x4{0.f, 0.f, 0.f, 0.f};

  // staging: slot = i*256+t -> r = slot>>4, c = slot&15; global chunk c^(r&7)
  auto stg = [&](int buf, int s) {
    #pragma unroll
    for (int i = 0; i < 2; ++i) {
      int slot = i * 256 + t, r = slot >> 4, c = slot & 15;
      GLOAD(Ablk + (size_t)r * KAUG + s * 128 + (c ^ (r & 7)) * 8,
            LA + buf * 4096 + i * 2048 + w * 512);
    }
    #pragma unroll
    for (int i = 0; i < 8; ++i) {
      int slot = i * 256 + t, r = slot >> 4, c = slot & 15;
      GLOAD(Ac + (size_t)r * IN_F + s * 128 + (c ^ (r & 7)) * 8,
            LB + buf * 16384 + i * 2048 + w * 512);
    }
  };

  stg(0, 0); stg(1, 1);
  for (int s = 0; s < 16; ++s) {
    if (s == 15) { WAITV0(); } else { WAITV10(); }
    PIN(); BAR();
    if (s + 2 < 16) stg((s + 2) % 3, s + 2);
    const int buf = s % 3;
    bf16x8 xf[2][2][2], bf[2][2][2];   // [khalf][mi|ni][ks]
    #pragma unroll
    for (int kh = 0; kh < 2; ++kh)
      #pragma unroll
      for (int mi = 0; mi < 2; ++mi)
        #pragma unroll
        for (int ks = 0; ks < 2; ++ks) {
          int row = mi * 16 + lr;
          int ch = kh * 8 + ks * 4 + lq;
          xf[kh][mi][ks] = *(const bf16x8*)(LA + buf * 4096 + row * 128 + (ch ^ (row & 7)) * 8);
        }
    #pragma unroll
    for (int kh = 0; kh < 2; ++kh)
      #pragma unroll
      for (int ni = 0; ni < 2; ++ni)
        #pragma unroll
        for (int ks = 0; ks < 2; ++ks) {
          int row = w * 32 + ni * 16 + lr;
          int ch = kh * 8 + ks * 4 + lq;
          bf[kh][ni][ks] = *(const bf16x8*)(LB + buf * 16384 + row * 128 + (ch ^ (row & 7)) * 8);
        }
    #pragma unroll
    for (int kh = 0; kh < 2; ++kh)
      #pragma unroll
      for (int mi = 0; mi < 2; ++mi)
        #pragma unroll
        for (int ni = 0; ni < 2; ++ni)
          #pragma unroll
          for (int ks = 0; ks < 2; ++ks)
            acc[mi][ni] = __builtin_amdgcn_mfma_f32_16x16x32_bf16(
                xf[kh][mi][ks], bf[kh][ni][ks], acc[mi][ni], 0, 0, 0);
  }

  #pragma unroll
  for (int mi = 0; mi < 2; ++mi)
    #pragma unroll
    for (int ni = 0; ni < 2; ++ni)
      #pragma unroll
      for (int j = 0; j < 4; ++j) {
        int row = bm * 32 + mi * 16 + lq * 4 + j;
        int col = w * 32 + ni * 16 + lr;
        float sg = wsc[row * 8 + (col >> 4)];
        Vout[(size_t)row * KAUG + col] = f2b(acc[mi][ni][j] * sg);
      }
}

// ---------------------------------------------------------------------------
// Main GEMM: 8-phase / 2-K-tile schedule, single barrier per phase
// (R11-proven, byte-identical).
// ---------------------------------------------------------------------------
__global__ __launch_bounds__(512, 2)
void k_main(const unsigned short* __restrict__ A, const unsigned short* __restrict__ B,
            float* __restrict__ out) {
  __shared__ alignas(16) unsigned short LDS[65536];   // A: [0,32768) B: [32768,65536) shorts

  const int tid = threadIdx.x;
  const int id = blockIdx.x;
  const int wg = (id & 7) * 32 + (id >> 3);   // XCD-contiguous
  const int bn = wg >> 5, bm = wg & 31;
  const int w = tid >> 6, l = tid & 63;
  const int wr = w >> 2, wc = w & 3;
  const int lr = l & 15, lq = l >> 4, lx = l & 7;

  const unsigned short* Ablk = A + (size_t)bm * 256 * KAUG;
  const unsigned short* Bblk = B + (size_t)bn * 256 * KAUG;

  const size_t gofs0 = (size_t)(tid >> 3) * KAUG + (size_t)(((tid & 7) ^ ((tid >> 3) & 7)) * 8);
  const size_t gofs1 = (size_t)((tid + 512) >> 3) * KAUG +
                       (size_t)((((tid + 512) & 7) ^ (((tid + 512) >> 3) & 7)) * 8);
  unsigned short* const ldsW = LDS + w * 512;   // wave-uniform dest base

  const int arow = wr * 128 + lr, brow = wc * 64 + lr;
  const int sl0 = (lq ^ lx) * 8, sl1 = ((4 + lq) ^ lx) * 8;

  f32x4 acc[8][4];
  #pragma unroll
  for (int i = 0; i < 8; ++i)
    #pragma unroll
    for (int j = 0; j < 4; ++j) acc[i][j] = f32x4{0.f, 0.f, 0.f, 0.f};
  bf16x8 aF[4][2], bF[4][2];

  auto stage = [&](int isB, int half, int kt) {
    if (kt >= NT64) return;
    const unsigned short* g = (isB ? Bblk : Ablk) + (size_t)(half * 128) * KAUG + (size_t)kt * 64;
    unsigned short* ld = ldsW + isB * 32768 + (kt & 1) * 16384 + half * 8192;
    GLOAD(g + gofs0, ld);
    GLOAD(g + gofs1, ld + 4096);
  };

#define QUAD(MQ, NQ)                                                                     \
  do {                                                                                   \
    _Pragma("unroll") for (int mi_ = 0; mi_ < 4; ++mi_)                                  \
    _Pragma("unroll") for (int ni_ = 0; ni_ < 2; ++ni_)                                  \
    _Pragma("unroll") for (int ks_ = 0; ks_ < 2; ++ks_)                                  \
      acc[(MQ)*4 + mi_][(NQ)*2 + ni_] = __builtin_amdgcn_mfma_f32_16x16x32_bf16(         \
          aF[mi_][ks_], bF[(NQ)*2 + ni_][ks_], acc[(MQ)*4 + mi_][(NQ)*2 + ni_],          \
          0, 0, 0);                                                                      \
  } while (0)

  // prologue: tile0 full + B-halves of tile1; vmcnt(4) -> tile0 resident
  stage(1, 0, 0); stage(1, 1, 0); stage(0, 0, 0); stage(0, 1, 0);
  stage(1, 0, 1); stage(1, 1, 1);
  WAITV4(); PIN(); BAR();

  for (int i = 0; i < NITER; ++i) {
    const int k1 = 2 * i + 1;
    const int a0 = arow * 64,   b0 = 32768 + brow * 64;    // even tile -> buf0
    const int a1 = a0 + 16384,  b1 = b0 + 16384;           // odd tile  -> buf1

    // ---- ph1
    #pragma unroll
    for (int mi = 0; mi < 4; ++mi) {
      aF[mi][0] = *(const bf16x8*)(LDS + a0 + mi * 1024 + sl0);
      aF[mi][1] = *(const bf16x8*)(LDS + a0 + mi * 1024 + sl1);
    }
    #pragma unroll
    for (int ni = 0; ni < 2; ++ni) {
      bF[ni][0] = *(const bf16x8*)(LDS + b0 + ni * 1024 + sl0);
      bF[ni][1] = *(const bf16x8*)(LDS + b0 + ni * 1024 + sl1);
    }
    stage(0, 0, k1);
    PIN(); WAITL(); SB0();
    __builtin_amdgcn_s_setprio(1); QUAD(0, 0); __builtin_amdgcn_s_setprio(0);
    PIN(); BAR();
    // ---- ph2
    #pragma unroll
    for (int ni = 2; ni < 4; ++ni) {
      bF[ni][0] = *(const bf16x8*)(LDS + b0 + ni * 1024 + sl0);
      bF[ni][1] = *(const bf16x8*)(LDS + b0 + ni * 1024 + sl1);
    }
    stage(0, 1, k1);
    PIN(); WAITL(); SB0();
    __builtin_amdgcn_s_setprio(1); QUAD(0, 1); __builtin_amdgcn_s_setprio(0);
    PIN(); BAR();
    // ---- ph3
    #pragma unroll
    for (int mi = 0; mi < 4; ++mi) {
      aF[mi][0] = *(const bf16x8*)(LDS + a0 + (mi + 4) * 1024 + sl0);
      aF[mi][1] = *(const bf16x8*)(LDS + a0 + (mi + 4) * 1024 + sl1);
    }
    stage(1, 0, k1 + 1);
    PIN(); WAITL(); SB0();
    __builtin_amdgcn_s_setprio(1); QUAD(1, 1); __builtin_amdgcn_s_setprio(0);
    PIN(); BAR();
    // ---- ph4
    stage(1, 1, k1 + 1);
    PIN();
    __builtin_amdgcn_s_setprio(1); QUAD(1, 0); __builtin_amdgcn_s_setprio(0);
    PIN();
    if (i == NITER - 1) { WAITV0(); } else { WAITV4(); }
    PIN(); BAR();

    // ---- ph5
    #pragma unroll
    for (int mi = 0; mi < 4; ++mi) {
      aF[mi][0] = *(const bf16x8*)(LDS + a1 + mi * 1024 + sl0);
      aF[mi][1] = *(const bf16x8*)(LDS + a1 + mi * 1024 + sl1);
    }
    #pragma unroll
    for (int ni = 0; ni < 2; ++ni) {
      bF[ni][0] = *(const bf16x8*)(LDS + b1 + ni * 1024 + sl0);
      bF[ni][1] = *(const bf16x8*)(LDS + b1 + ni * 1024 + sl1);
    }
    stage(0, 0, k1 + 1);
    PIN(); WAITL(); SB0();
    __builtin_amdgcn_s_setprio(1); QUAD(0, 0); __builtin_amdgcn_s_setprio(0);
    PIN(); BAR();
    // ---- ph6
    #pragma unroll
    for (int ni = 2; ni < 4; ++ni) {
      bF[ni][0] = *(const bf16x8*)(LDS + b1 + ni * 1024 + sl0);
      bF[ni][1] = *(const bf16x8*)(LDS + b1 + ni * 1024 + sl1);
    }
    stage(0, 1, k1 + 1);
    PIN(); WAITL(); SB0();
    __builtin_amdgcn_s_setprio(1); QUAD(0, 1); __builtin_amdgcn_s_setprio(0);
    PIN(); BAR();
    // ---- ph7
    #pragma unroll
    for (int mi = 0; mi < 4; ++mi) {
      aF[mi][0] = *(const bf16x8*)(LDS + a1 + (mi + 4) * 1024 + sl0);
      aF[mi][1] = *(const bf16x8*)(LDS + a1 + (mi + 4) * 1024 + sl1);
    }
    stage(1, 0, k1 + 2);
    PIN(); WAITL(); SB0();
    __builtin_amdgcn_s_setprio(1); QUAD(1, 1); __builtin_amdgcn_s_setprio(0);
    PIN(); BAR();
    // ---- ph8
    stage(1, 1, k1 + 2);
    PIN();
    __builtin_amdgcn_s_setprio(1); QUAD(1, 0); __builtin_amdgcn_s_setprio(0);
    PIN();
    if (i == NITER - 1) { WAITV0(); } else { WAITV4(); }
    PIN(); BAR();
  }
#undef QUAD

  #pragma unroll
  for (int mi = 0; mi < 8; ++mi)
    #pragma unroll
    for (int ni = 0; ni < 4; ++ni)
      #pragma unroll
      for (int j = 0; j < 4; ++j) {
        int row = bm * 256 + wr * 128 + mi * 16 + lq * 4 + j;
        int col = bn * 256 + wc * 64 + ni * 16 + lr;
        out[(size_t)row * OUT_F + col] = acc[mi][ni][j];
      }
}

extern "C" void kernel_launch(void* const* d_in, const int* in_sizes, int n_in,
                              void* d_out, int out_size, void* d_ws, size_t ws_size,
                              hipStream_t stream) {
  const float* x  = (const float*)d_in[0];
  const float* wt = (const float*)d_in[1];
  const float* la = (const float*)d_in[2];
  const float* lb = (const float*)d_in[3];
  const float* rw = (const float*)d_in[4];
  float* out = (float*)d_out;
  char* ws = (char*)d_ws;

  unsigned short* Ap  = (unsigned short*)ws;                 // bf16 [8192][2176]
  unsigned short* Bp  = (unsigned short*)(ws + 35651584);    // bf16 [2048][2176]
  unsigned short* Ac  = (unsigned short*)(ws + 44564480);    // bf16 [128][2048]
  float*          wsc = (float*)(ws + 45088768);             // f32  [8192][8]

  k_pre<<<3080, 256, 0, stream>>>(x, rw, wt, lb, la, Ap, wsc, Bp, Ac);
  k_lora<<<NTOK / 32, 256, 0, stream>>>(Ap, Ac, wsc, Ap + IN_F);
  k_main<<<256, 512, 0, stream>>>(Ap, Bp, out);
}

// Round 14
// 119.130 us; speedup vs baseline: 1.0742x; 1.0355x over previous
//
#include <hip/hip_runtime.h>
#include <hip/hip_bf16.h>
#include <stdint.h>

#define IN_F   2048
#define OUT_F  2048
#define NTOK   8192
#define KAUG   2176   // 2048 + E*R
#define RANKE  128    // E*R
#define SCALING 2.0f
#define NT64   34     // KAUG / 64
#define NITER  17     // NT64 / 2

typedef float  f32x4 __attribute__((ext_vector_type(4)));
typedef __bf16 bf16x8 __attribute__((ext_vector_type(8)));

#define GLOAD(g, l) __builtin_amdgcn_global_load_lds(                                   \
    (const __attribute__((address_space(1))) unsigned int*)(g),                          \
    (__attribute__((address_space(3))) unsigned int*)(l), 16, 0, 0)
#define PIN()    asm volatile("" ::: "memory")
#define BAR()    __builtin_amdgcn_s_barrier()
#define WAITL()  asm volatile("s_waitcnt lgkmcnt(0)" ::: "memory")
#define WAITV0() asm volatile("s_waitcnt vmcnt(0)" ::: "memory")
#define WAITV4() asm volatile("s_waitcnt vmcnt(4)" ::: "memory")
#define WAITV10() asm volatile("s_waitcnt vmcnt(10)" ::: "memory")
#define SB0()    __builtin_amdgcn_sched_barrier(0)

__device__ __forceinline__ unsigned short f2b(float f) {
  union { float f; unsigned u; } v; v.f = f;
  return (unsigned short)((v.u + 0x7FFFu + ((v.u >> 16) & 1u)) >> 16);
}

__device__ __forceinline__ uint4 pack8(float4 a, float4 b) {
  uint4 p;
  p.x = f2b(a.x) | ((unsigned)f2b(a.y) << 16);
  p.y = f2b(a.z) | ((unsigned)f2b(a.w) << 16);
  p.z = f2b(b.x) | ((unsigned)f2b(b.y) << 16);
  p.w = f2b(b.z) | ((unsigned)f2b(b.w) << 16);
  return p;
}

// ---------------------------------------------------------------------------
// Merged pre-pass v3. Role by blockIdx:
//   [0,1024):     prep (8 tokens: x->bf16 16B-stores + router) AND B' rows
//                 [2*bid, 2*bid+2) — independent streams fill latency bubbles
//   [1024,1032):  convert lora_A -> Acat bf16
// ---------------------------------------------------------------------------
__global__ __launch_bounds__(256)
void k_pre(const float* __restrict__ x, const float* __restrict__ rw,
           const float* __restrict__ wt, const float* __restrict__ lb,
           const float* __restrict__ la,
           unsigned short* __restrict__ Ap, float* __restrict__ wsc,
           unsigned short* __restrict__ Bp, unsigned short* __restrict__ Ac) {
  const int bid = blockIdx.x;
  const int t = threadIdx.x;

  if (bid >= 1024) {          // ---- convert lora_A: 8 blocks x 16 rows
    const int r0 = (bid - 1024) * 16;
    #pragma unroll
    for (int j = 0; j < 16; ++j) {
      int ch = j * 256 + t;
      int row = r0 + (ch >> 8), col8 = ch & 255;
      const float4* src = (const float4*)(la + (size_t)row * IN_F + col8 * 8);
      *(uint4*)(Ac + (size_t)row * IN_F + col8 * 8) = pack8(src[0], src[1]);
    }
    return;
  }

  const int w = t >> 6, l = t & 63;
  const int n0 = bid * 8 + w * 2;

  // ---- x load (32B/lane contiguous) + convert + 16B store; keep regs
  float4 xr[2][4][2];
  #pragma unroll
  for (int ti = 0; ti < 2; ++ti) {
    const float4* xp = (const float4*)(x + (size_t)(n0 + ti) * IN_F);
    uint4* dst = (uint4*)(Ap + (size_t)(n0 + ti) * KAUG);
    #pragma unroll
    for (int j = 0; j < 4; ++j) {
      int c = j * 64 + l;
      float4 a = xp[2 * c], b = xp[2 * c + 1];
      xr[ti][j][0] = a; xr[ti][j][1] = b;
      dst[c] = pack8(a, b);
    }
  }

  // ---- B' build: rows 2*bid, 2*bid+1 (independent stream, fills bubbles)
  #pragma unroll
  for (int r = 0; r < 2; ++r) {
    const int o = bid * 2 + r;
    const float4* src = (const float4*)(wt + (size_t)o * IN_F + t * 8);
    *(uint4*)(Bp + (size_t)o * KAUG + t * 8) = pack8(src[0], src[1]);
    if (t < RANKE) {
      float v = lb[((size_t)(t >> 4) * OUT_F + o) * 16 + (t & 15)];
      Bp[(size_t)o * KAUG + IN_F + t] = f2b(v);
    }
  }

  // ---- router: stream rw with matching 32B/lane pattern
  float acc[2][8];
  #pragma unroll
  for (int ti = 0; ti < 2; ++ti)
    #pragma unroll
    for (int e = 0; e < 8; ++e) acc[ti][e] = 0.f;
  #pragma unroll
  for (int e = 0; e < 8; ++e) {
    const float4* wp = (const float4*)(rw + (size_t)e * IN_F);
    #pragma unroll
    for (int j = 0; j < 4; ++j) {
      int c = j * 64 + l;
      float4 ba = wp[2 * c], bb = wp[2 * c + 1];
      #pragma unroll
      for (int ti = 0; ti < 2; ++ti) {
        acc[ti][e] += xr[ti][j][0].x * ba.x + xr[ti][j][0].y * ba.y +
                      xr[ti][j][0].z * ba.z + xr[ti][j][0].w * ba.w;
        acc[ti][e] += xr[ti][j][1].x * bb.x + xr[ti][j][1].y * bb.y +
                      xr[ti][j][1].z * bb.z + xr[ti][j][1].w * bb.w;
      }
    }
  }
  // full-wave butterfly: every lane gets complete logits
  #pragma unroll
  for (int ti = 0; ti < 2; ++ti)
    #pragma unroll
    for (int e = 0; e < 8; ++e) {
      #pragma unroll
      for (int msk = 1; msk <= 32; msk <<= 1) acc[ti][e] += __shfl_xor(acc[ti][e], msk);
    }
  // scalar softmax + top2; lanes [8ti, 8ti+8) write
  #pragma unroll
  for (int ti = 0; ti < 2; ++ti) {
    float m = acc[ti][0];
    #pragma unroll
    for (int e = 1; e < 8; ++e) m = fmaxf(m, acc[ti][e]);
    float ex[8], dn = 0.f;
    #pragma unroll
    for (int e = 0; e < 8; ++e) { ex[e] = expf(acc[ti][e] - m); dn += ex[e]; }
    float inv = 1.f / dn;
    float v1 = -1.f; int i1 = 0;
    #pragma unroll
    for (int e = 0; e < 8; ++e) {
      float p = ex[e] * inv;
      if (p > v1) { v1 = p; i1 = e; }
    }
    float v2 = -1.f; int i2 = 0;
    #pragma unroll
    for (int e = 0; e < 8; ++e) {
      float p = ex[e] * inv;
      if (e != i1 && p > v2) { v2 = p; i2 = e; }
    }
    if ((l >> 3) == ti) {
      int e = l & 7;
      float wsum = v1 + v2;
      float wv = (e == i1) ? (v1 / wsum) : ((e == i2) ? (v2 / wsum) : 0.f);
      wsc[(size_t)(n0 + ti) * 8 + e] = wv * SCALING;
    }
  }
}

// ---------------------------------------------------------------------------
// LoRA-A GEMM v2 (R13-proven, unchanged): 32x128 tile, ring-3 K=128 LDS,
// counted vmcnt(10), chunk^(row&7) swizzle on global source.
// ---------------------------------------------------------------------------
__global__ __launch_bounds__(256)
void k_lora(const unsigned short* __restrict__ Ap, const unsigned short* __restrict__ Ac,
            const float* __restrict__ wsc, unsigned short* __restrict__ Vout) {
  __shared__ alignas(16) unsigned short LA[3 * 4096];    // 3 x [32][128]  (24KB)
  __shared__ alignas(16) unsigned short LB[3 * 16384];   // 3 x [128][128] (96KB)
  const int t = threadIdx.x, bm = blockIdx.x;
  const int w = t >> 6, l = t & 63;
  const int lr = l & 15, lq = l >> 4;
  const unsigned short* Ablk = Ap + (size_t)bm * 32 * KAUG;

  f32x4 acc[2][2];
  #pragma unroll
  for (int i = 0; i < 2; ++i)
    #pragma unroll
    for (int j = 0; j < 2; ++j) acc[i][j] = f32x4{0.f, 0.f, 0.f, 0.f};

  auto stg = [&](int buf, int s) {
    #pragma unroll
    for (int i = 0; i < 2; ++i) {
      int slot = i * 256 + t, r = slot >> 4, c = slot & 15;
      GLOAD(Ablk + (size_t)r * KAUG + s * 128 + (c ^ (r & 7)) * 8,
            LA + buf * 4096 + i * 2048 + w * 512);
    }
    #pragma unroll
    for (int i = 0; i < 8; ++i) {
      int slot = i * 256 + t, r = slot >> 4, c = slot & 15;
      GLOAD(Ac + (size_t)r * IN_F + s * 128 + (c ^ (r & 7)) * 8,
            LB + buf * 16384 + i * 2048 + w * 512);
    }
  };

  stg(0, 0); stg(1, 1);
  for (int s = 0; s < 16; ++s) {
    if (s == 15) { WAITV0(); } else { WAITV10(); }
    PIN(); BAR();
    if (s + 2 < 16) stg((s + 2) % 3, s + 2);
    const int buf = s % 3;
    bf16x8 xf[2][2][2], bf[2][2][2];   // [khalf][mi|ni][ks]
    #pragma unroll
    for (int kh = 0; kh < 2; ++kh)
      #pragma unroll
      for (int mi = 0; mi < 2; ++mi)
        #pragma unroll
        for (int ks = 0; ks < 2; ++ks) {
          int row = mi * 16 + lr;
          int ch = kh * 8 + ks * 4 + lq;
          xf[kh][mi][ks] = *(const bf16x8*)(LA + buf * 4096 + row * 128 + (ch ^ (row & 7)) * 8);
        }
    #pragma unroll
    for (int kh = 0; kh < 2; ++kh)
      #pragma unroll
      for (int ni = 0; ni < 2; ++ni)
        #pragma unroll
        for (int ks = 0; ks < 2; ++ks) {
          int row = w * 32 + ni * 16 + lr;
          int ch = kh * 8 + ks * 4 + lq;
          bf[kh][ni][ks] = *(const bf16x8*)(LB + buf * 16384 + row * 128 + (ch ^ (row & 7)) * 8);
        }
    #pragma unroll
    for (int kh = 0; kh < 2; ++kh)
      #pragma unroll
      for (int mi = 0; mi < 2; ++mi)
        #pragma unroll
        for (int ni = 0; ni < 2; ++ni)
          #pragma unroll
          for (int ks = 0; ks < 2; ++ks)
            acc[mi][ni] = __builtin_amdgcn_mfma_f32_16x16x32_bf16(
                xf[kh][mi][ks], bf[kh][ni][ks], acc[mi][ni], 0, 0, 0);
  }

  #pragma unroll
  for (int mi = 0; mi < 2; ++mi)
    #pragma unroll
    for (int ni = 0; ni < 2; ++ni)
      #pragma unroll
      for (int j = 0; j < 4; ++j) {
        int row = bm * 32 + mi * 16 + lq * 4 + j;
        int col = w * 32 + ni * 16 + lr;
        float sg = wsc[row * 8 + (col >> 4)];
        Vout[(size_t)row * KAUG + col] = f2b(acc[mi][ni][j] * sg);
      }
}

// ---------------------------------------------------------------------------
// Main GEMM: 8-phase / 2-K-tile schedule, single barrier per phase
// (R11-proven, byte-identical).
// ---------------------------------------------------------------------------
__global__ __launch_bounds__(512, 2)
void k_main(const unsigned short* __restrict__ A, const unsigned short* __restrict__ B,
            float* __restrict__ out) {
  __shared__ alignas(16) unsigned short LDS[65536];   // A: [0,32768) B: [32768,65536) shorts

  const int tid = threadIdx.x;
  const int id = blockIdx.x;
  const int wg = (id & 7) * 32 + (id >> 3);   // XCD-contiguous
  const int bn = wg >> 5, bm = wg & 31;
  const int w = tid >> 6, l = tid & 63;
  const int wr = w >> 2, wc = w & 3;
  const int lr = l & 15, lq = l >> 4, lx = l & 7;

  const unsigned short* Ablk = A + (size_t)bm * 256 * KAUG;
  const unsigned short* Bblk = B + (size_t)bn * 256 * KAUG;

  const size_t gofs0 = (size_t)(tid >> 3) * KAUG + (size_t)(((tid & 7) ^ ((tid >> 3) & 7)) * 8);
  const size_t gofs1 = (size_t)((tid + 512) >> 3) * KAUG +
                       (size_t)((((tid + 512) & 7) ^ (((tid + 512) >> 3) & 7)) * 8);
  unsigned short* const ldsW = LDS + w * 512;   // wave-uniform dest base

  const int arow = wr * 128 + lr, brow = wc * 64 + lr;
  const int sl0 = (lq ^ lx) * 8, sl1 = ((4 + lq) ^ lx) * 8;

  f32x4 acc[8][4];
  #pragma unroll
  for (int i = 0; i < 8; ++i)
    #pragma unroll
    for (int j = 0; j < 4; ++j) acc[i][j] = f32x4{0.f, 0.f, 0.f, 0.f};
  bf16x8 aF[4][2], bF[4][2];

  auto stage = [&](int isB, int half, int kt) {
    if (kt >= NT64) return;
    const unsigned short* g = (isB ? Bblk : Ablk) + (size_t)(half * 128) * KAUG + (size_t)kt * 64;
    unsigned short* ld = ldsW + isB * 32768 + (kt & 1) * 16384 + half * 8192;
    GLOAD(g + gofs0, ld);
    GLOAD(g + gofs1, ld + 4096);
  };

#define QUAD(MQ, NQ)                                                                     \
  do {                                                                                   \
    _Pragma("unroll") for (int mi_ = 0; mi_ < 4; ++mi_)                                  \
    _Pragma("unroll") for (int ni_ = 0; ni_ < 2; ++ni_)                                  \
    _Pragma("unroll") for (int ks_ = 0; ks_ < 2; ++ks_)                                  \
      acc[(MQ)*4 + mi_][(NQ)*2 + ni_] = __builtin_amdgcn_mfma_f32_16x16x32_bf16(         \
          aF[mi_][ks_], bF[(NQ)*2 + ni_][ks_], acc[(MQ)*4 + mi_][(NQ)*2 + ni_],          \
          0, 0, 0);                                                                      \
  } while (0)

  // prologue: tile0 full + B-halves of tile1; vmcnt(4) -> tile0 resident
  stage(1, 0, 0); stage(1, 1, 0); stage(0, 0, 0); stage(0, 1, 0);
  stage(1, 0, 1); stage(1, 1, 1);
  WAITV4(); PIN(); BAR();

  for (int i = 0; i < NITER; ++i) {
    const int k1 = 2 * i + 1;
    const int a0 = arow * 64,   b0 = 32768 + brow * 64;    // even tile -> buf0
    const int a1 = a0 + 16384,  b1 = b0 + 16384;           // odd tile  -> buf1

    // ---- ph1
    #pragma unroll
    for (int mi = 0; mi < 4; ++mi) {
      aF[mi][0] = *(const bf16x8*)(LDS + a0 + mi * 1024 + sl0);
      aF[mi][1] = *(const bf16x8*)(LDS + a0 + mi * 1024 + sl1);
    }
    #pragma unroll
    for (int ni = 0; ni < 2; ++ni) {
      bF[ni][0] = *(const bf16x8*)(LDS + b0 + ni * 1024 + sl0);
      bF[ni][1] = *(const bf16x8*)(LDS + b0 + ni * 1024 + sl1);
    }
    stage(0, 0, k1);
    PIN(); WAITL(); SB0();
    __builtin_amdgcn_s_setprio(1); QUAD(0, 0); __builtin_amdgcn_s_setprio(0);
    PIN(); BAR();
    // ---- ph2
    #pragma unroll
    for (int ni = 2; ni < 4; ++ni) {
      bF[ni][0] = *(const bf16x8*)(LDS + b0 + ni * 1024 + sl0);
      bF[ni][1] = *(const bf16x8*)(LDS + b0 + ni * 1024 + sl1);
    }
    stage(0, 1, k1);
    PIN(); WAITL(); SB0();
    __builtin_amdgcn_s_setprio(1); QUAD(0, 1); __builtin_amdgcn_s_setprio(0);
    PIN(); BAR();
    // ---- ph3
    #pragma unroll
    for (int mi = 0; mi < 4; ++mi) {
      aF[mi][0] = *(const bf16x8*)(LDS + a0 + (mi + 4) * 1024 + sl0);
      aF[mi][1] = *(const bf16x8*)(LDS + a0 + (mi + 4) * 1024 + sl1);
    }
    stage(1, 0, k1 + 1);
    PIN(); WAITL(); SB0();
    __builtin_amdgcn_s_setprio(1); QUAD(1, 1); __builtin_amdgcn_s_setprio(0);
    PIN(); BAR();
    // ---- ph4
    stage(1, 1, k1 + 1);
    PIN();
    __builtin_amdgcn_s_setprio(1); QUAD(1, 0); __builtin_amdgcn_s_setprio(0);
    PIN();
    if (i == NITER - 1) { WAITV0(); } else { WAITV4(); }
    PIN(); BAR();

    // ---- ph5
    #pragma unroll
    for (int mi = 0; mi < 4; ++mi) {
      aF[mi][0] = *(const bf16x8*)(LDS + a1 + mi * 1024 + sl0);
      aF[mi][1] = *(const bf16x8*)(LDS + a1 + mi * 1024 + sl1);
    }
    #pragma unroll
    for (int ni = 0; ni < 2; ++ni) {
      bF[ni][0] = *(const bf16x8*)(LDS + b1 + ni * 1024 + sl0);
      bF[ni][1] = *(const bf16x8*)(LDS + b1 + ni * 1024 + sl1);
    }
    stage(0, 0, k1 + 1);
    PIN(); WAITL(); SB0();
    __builtin_amdgcn_s_setprio(1); QUAD(0, 0); __builtin_amdgcn_s_setprio(0);
    PIN(); BAR();
    // ---- ph6
    #pragma unroll
    for (int ni = 2; ni < 4; ++ni) {
      bF[ni][0] = *(const bf16x8*)(LDS + b1 + ni * 1024 + sl0);
      bF[ni][1] = *(const bf16x8*)(LDS + b1 + ni * 1024 + sl1);
    }
    stage(0, 1, k1 + 1);
    PIN(); WAITL(); SB0();
    __builtin_amdgcn_s_setprio(1); QUAD(0, 1); __builtin_amdgcn_s_setprio(0);
    PIN(); BAR();
    // ---- ph7
    #pragma unroll
    for (int mi = 0; mi < 4; ++mi) {
      aF[mi][0] = *(const bf16x8*)(LDS + a1 + (mi + 4) * 1024 + sl0);
      aF[mi][1] = *(const bf16x8*)(LDS + a1 + (mi + 4) * 1024 + sl1);
    }
    stage(1, 0, k1 + 2);
    PIN(); WAITL(); SB0();
    __builtin_amdgcn_s_setprio(1); QUAD(1, 1); __builtin_amdgcn_s_setprio(0);
    PIN(); BAR();
    // ---- ph8
    stage(1, 1, k1 + 2);
    PIN();
    __builtin_amdgcn_s_setprio(1); QUAD(1, 0); __builtin_amdgcn_s_setprio(0);
    PIN();
    if (i == NITER - 1) { WAITV0(); } else { WAITV4(); }
    PIN(); BAR();
  }
#undef QUAD

  #pragma unroll
  for (int mi = 0; mi < 8; ++mi)
    #pragma unroll
    for (int ni = 0; ni < 4; ++ni)
      #pragma unroll
      for (int j = 0; j < 4; ++j) {
        int row = bm * 256 + wr * 128 + mi * 16 + lq * 4 + j;
        int col = bn * 256 + wc * 64 + ni * 16 + lr;
        out[(size_t)row * OUT_F + col] = acc[mi][ni][j];
      }
}

extern "C" void kernel_launch(void* const* d_in, const int* in_sizes, int n_in,
                              void* d_out, int out_size, void* d_ws, size_t ws_size,
                              hipStream_t stream) {
  const float* x  = (const float*)d_in[0];
  const float* wt = (const float*)d_in[1];
  const float* la = (const float*)d_in[2];
  const float* lb = (const float*)d_in[3];
  const float* rw = (const float*)d_in[4];
  float* out = (float*)d_out;
  char* ws = (char*)d_ws;

  unsigned short* Ap  = (unsigned short*)ws;                 // bf16 [8192][2176]
  unsigned short* Bp  = (unsigned short*)(ws + 35651584);    // bf16 [2048][2176]
  unsigned short* Ac  = (unsigned short*)(ws + 44564480);    // bf16 [128][2048]
  float*          wsc = (float*)(ws + 45088768);             // f32  [8192][8]

  k_pre<<<1032, 256, 0, stream>>>(x, rw, wt, lb, la, Ap, wsc, Bp, Ac);
  k_lora<<<NTOK / 32, 256, 0, stream>>>(Ap, Ac, wsc, Ap + IN_F);
  k_main<<<256, 512, 0, stream>>>(Ap, Bp, out);
}

// Round 15
// 115.906 us; speedup vs baseline: 1.1041x; 1.0278x over previous
//
#include <hip/hip_runtime.h>
#include <hip/hip_bf16.h>
#include <stdint.h>

#define IN_F   2048
#define OUT_F  2048
#define NTOK   8192
#define KAUG   2176   // 2048 + E*R
#define RANKE  128    // E*R
#define SCALING 2.0f
#define NT64   34     // KAUG / 64
#define NITER  17     // NT64 / 2

typedef float  f32x4 __attribute__((ext_vector_type(4)));
typedef __bf16 bf16x8 __attribute__((ext_vector_type(8)));

#define GLOAD(g, l) __builtin_amdgcn_global_load_lds(                                   \
    (const __attribute__((address_space(1))) unsigned int*)(g),                          \
    (__attribute__((address_space(3))) unsigned int*)(l), 16, 0, 0)
#define PIN()    asm volatile("" ::: "memory")
#define BAR()    __builtin_amdgcn_s_barrier()
#define WAITL()  asm volatile("s_waitcnt lgkmcnt(0)" ::: "memory")
#define WAITV0() asm volatile("s_waitcnt vmcnt(0)" ::: "memory")
#define WAITV4() asm volatile("s_waitcnt vmcnt(4)" ::: "memory")
#define WAITV10() asm volatile("s_waitcnt vmcnt(10)" ::: "memory")
#define SB0()    __builtin_amdgcn_sched_barrier(0)

__device__ __forceinline__ unsigned short f2b(float f) {
  union { float f; unsigned u; } v; v.f = f;
  return (unsigned short)((v.u + 0x7FFFu + ((v.u >> 16) & 1u)) >> 16);
}

__device__ __forceinline__ uint4 pack8(float4 a, float4 b) {
  uint4 p;
  p.x = f2b(a.x) | ((unsigned)f2b(a.y) << 16);
  p.y = f2b(a.z) | ((unsigned)f2b(a.w) << 16);
  p.z = f2b(b.x) | ((unsigned)f2b(b.y) << 16);
  p.w = f2b(b.z) | ((unsigned)f2b(b.w) << 16);
  return p;
}

// ---------------------------------------------------------------------------
// Merged pre-pass v3 (R14-proven, unchanged). Role by blockIdx:
//   [0,1024):     prep (8 tokens: x->bf16 16B-stores + router) AND B' rows
//   [1024,1032):  convert lora_A -> Acat bf16
// ---------------------------------------------------------------------------
__global__ __launch_bounds__(256)
void k_pre(const float* __restrict__ x, const float* __restrict__ rw,
           const float* __restrict__ wt, const float* __restrict__ lb,
           const float* __restrict__ la,
           unsigned short* __restrict__ Ap, float* __restrict__ wsc,
           unsigned short* __restrict__ Bp, unsigned short* __restrict__ Ac) {
  const int bid = blockIdx.x;
  const int t = threadIdx.x;

  if (bid >= 1024) {          // ---- convert lora_A: 8 blocks x 16 rows
    const int r0 = (bid - 1024) * 16;
    #pragma unroll
    for (int j = 0; j < 16; ++j) {
      int ch = j * 256 + t;
      int row = r0 + (ch >> 8), col8 = ch & 255;
      const float4* src = (const float4*)(la + (size_t)row * IN_F + col8 * 8);
      *(uint4*)(Ac + (size_t)row * IN_F + col8 * 8) = pack8(src[0], src[1]);
    }
    return;
  }

  const int w = t >> 6, l = t & 63;
  const int n0 = bid * 8 + w * 2;

  // ---- x load (32B/lane contiguous) + convert + 16B store; keep regs
  float4 xr[2][4][2];
  #pragma unroll
  for (int ti = 0; ti < 2; ++ti) {
    const float4* xp = (const float4*)(x + (size_t)(n0 + ti) * IN_F);
    uint4* dst = (uint4*)(Ap + (size_t)(n0 + ti) * KAUG);
    #pragma unroll
    for (int j = 0; j < 4; ++j) {
      int c = j * 64 + l;
      float4 a = xp[2 * c], b = xp[2 * c + 1];
      xr[ti][j][0] = a; xr[ti][j][1] = b;
      dst[c] = pack8(a, b);
    }
  }

  // ---- B' build: rows 2*bid, 2*bid+1 (independent stream, fills bubbles)
  #pragma unroll
  for (int r = 0; r < 2; ++r) {
    const int o = bid * 2 + r;
    const float4* src = (const float4*)(wt + (size_t)o * IN_F + t * 8);
    *(uint4*)(Bp + (size_t)o * KAUG + t * 8) = pack8(src[0], src[1]);
    if (t < RANKE) {
      float v = lb[((size_t)(t >> 4) * OUT_F + o) * 16 + (t & 15)];
      Bp[(size_t)o * KAUG + IN_F + t] = f2b(v);
    }
  }

  // ---- router: stream rw with matching 32B/lane pattern
  float acc[2][8];
  #pragma unroll
  for (int ti = 0; ti < 2; ++ti)
    #pragma unroll
    for (int e = 0; e < 8; ++e) acc[ti][e] = 0.f;
  #pragma unroll
  for (int e = 0; e < 8; ++e) {
    const float4* wp = (const float4*)(rw + (size_t)e * IN_F);
    #pragma unroll
    for (int j = 0; j < 4; ++j) {
      int c = j * 64 + l;
      float4 ba = wp[2 * c], bb = wp[2 * c + 1];
      #pragma unroll
      for (int ti = 0; ti < 2; ++ti) {
        acc[ti][e] += xr[ti][j][0].x * ba.x + xr[ti][j][0].y * ba.y +
                      xr[ti][j][0].z * ba.z + xr[ti][j][0].w * ba.w;
        acc[ti][e] += xr[ti][j][1].x * bb.x + xr[ti][j][1].y * bb.y +
                      xr[ti][j][1].z * bb.z + xr[ti][j][1].w * bb.w;
      }
    }
  }
  #pragma unroll
  for (int ti = 0; ti < 2; ++ti)
    #pragma unroll
    for (int e = 0; e < 8; ++e) {
      #pragma unroll
      for (int msk = 1; msk <= 32; msk <<= 1) acc[ti][e] += __shfl_xor(acc[ti][e], msk);
    }
  #pragma unroll
  for (int ti = 0; ti < 2; ++ti) {
    float m = acc[ti][0];
    #pragma unroll
    for (int e = 1; e < 8; ++e) m = fmaxf(m, acc[ti][e]);
    float ex[8], dn = 0.f;
    #pragma unroll
    for (int e = 0; e < 8; ++e) { ex[e] = expf(acc[ti][e] - m); dn += ex[e]; }
    float inv = 1.f / dn;
    float v1 = -1.f; int i1 = 0;
    #pragma unroll
    for (int e = 0; e < 8; ++e) {
      float p = ex[e] * inv;
      if (p > v1) { v1 = p; i1 = e; }
    }
    float v2 = -1.f; int i2 = 0;
    #pragma unroll
    for (int e = 0; e < 8; ++e) {
      float p = ex[e] * inv;
      if (e != i1 && p > v2) { v2 = p; i2 = e; }
    }
    if ((l >> 3) == ti) {
      int e = l & 7;
      float wsum = v1 + v2;
      float wv = (e == i1) ? (v1 / wsum) : ((e == i2) ? (v2 / wsum) : 0.f);
      wsc[(size_t)(n0 + ti) * 8 + e] = wv * SCALING;
    }
  }
}

// ---------------------------------------------------------------------------
// LoRA-A GEMM v2 (R13-proven, unchanged): 32x128 tile, ring-3 K=128 LDS,
// counted vmcnt(10), chunk^(row&7) swizzle on global source.
// ---------------------------------------------------------------------------
__global__ __launch_bounds__(256)
void k_lora(const unsigned short* __restrict__ Ap, const unsigned short* __restrict__ Ac,
            const float* __restrict__ wsc, unsigned short* __restrict__ Vout) {
  __shared__ alignas(16) unsigned short LA[3 * 4096];    // 3 x [32][128]  (24KB)
  __shared__ alignas(16) unsigned short LB[3 * 16384];   // 3 x [128][128] (96KB)
  const int t = threadIdx.x, bm = blockIdx.x;
  const int w = t >> 6, l = t & 63;
  const int lr = l & 15, lq = l >> 4;
  const unsigned short* Ablk = Ap + (size_t)bm * 32 * KAUG;

  f32x4 acc[2][2];
  #pragma unroll
  for (int i = 0; i < 2; ++i)
    #pragma unroll
    for (int j = 0; j < 2; ++j) acc[i][j] = f32x4{0.f, 0.f, 0.f, 0.f};

  auto stg = [&](int buf, int s) {
    #pragma unroll
    for (int i = 0; i < 2; ++i) {
      int slot = i * 256 + t, r = slot >> 4, c = slot & 15;
      GLOAD(Ablk + (size_t)r * KAUG + s * 128 + (c ^ (r & 7)) * 8,
            LA + buf * 4096 + i * 2048 + w * 512);
    }
    #pragma unroll
    for (int i = 0; i < 8; ++i) {
      int slot = i * 256 + t, r = slot >> 4, c = slot & 15;
      GLOAD(Ac + (size_t)r * IN_F + s * 128 + (c ^ (r & 7)) * 8,
            LB + buf * 16384 + i * 2048 + w * 512);
    }
  };

  stg(0, 0); stg(1, 1);
  for (int s = 0; s < 16; ++s) {
    if (s == 15) { WAITV0(); } else { WAITV10(); }
    PIN(); BAR();
    if (s + 2 < 16) stg((s + 2) % 3, s + 2);
    const int buf = s % 3;
    bf16x8 xf[2][2][2], bf[2][2][2];   // [khalf][mi|ni][ks]
    #pragma unroll
    for (int kh = 0; kh < 2; ++kh)
      #pragma unroll
      for (int mi = 0; mi < 2; ++mi)
        #pragma unroll
        for (int ks = 0; ks < 2; ++ks) {
          int row = mi * 16 + lr;
          int ch = kh * 8 + ks * 4 + lq;
          xf[kh][mi][ks] = *(const bf16x8*)(LA + buf * 4096 + row * 128 + (ch ^ (row & 7)) * 8);
        }
    #pragma unroll
    for (int kh = 0; kh < 2; ++kh)
      #pragma unroll
      for (int ni = 0; ni < 2; ++ni)
        #pragma unroll
        for (int ks = 0; ks < 2; ++ks) {
          int row = w * 32 + ni * 16 + lr;
          int ch = kh * 8 + ks * 4 + lq;
          bf[kh][ni][ks] = *(const bf16x8*)(LB + buf * 16384 + row * 128 + (ch ^ (row & 7)) * 8);
        }
    #pragma unroll
    for (int kh = 0; kh < 2; ++kh)
      #pragma unroll
      for (int mi = 0; mi < 2; ++mi)
        #pragma unroll
        for (int ni = 0; ni < 2; ++ni)
          #pragma unroll
          for (int ks = 0; ks < 2; ++ks)
            acc[mi][ni] = __builtin_amdgcn_mfma_f32_16x16x32_bf16(
                xf[kh][mi][ks], bf[kh][ni][ks], acc[mi][ni], 0, 0, 0);
  }

  #pragma unroll
  for (int mi = 0; mi < 2; ++mi)
    #pragma unroll
    for (int ni = 0; ni < 2; ++ni)
      #pragma unroll
      for (int j = 0; j < 4; ++j) {
        int row = bm * 32 + mi * 16 + lq * 4 + j;
        int col = w * 32 + ni * 16 + lr;
        float sg = wsc[row * 8 + (col >> 4)];
        Vout[(size_t)row * KAUG + col] = f2b(acc[mi][ni][j] * sg);
      }
}

// ---------------------------------------------------------------------------
// Main GEMM: 8-phase / 2-K-tile schedule, single barrier per phase
// (R11-proven). CHANGE vs R14: bm-major XCD remap — each XCD runs 4
// contiguous bm panels x all 8 bn (working set 13.3MB vs 36.7MB bn-major).
// ---------------------------------------------------------------------------
__global__ __launch_bounds__(512, 2)
void k_main(const unsigned short* __restrict__ A, const unsigned short* __restrict__ B,
            float* __restrict__ out) {
  __shared__ alignas(16) unsigned short LDS[65536];   // A: [0,32768) B: [32768,65536) shorts

  const int tid = threadIdx.x;
  const int id = blockIdx.x;
  const int xcd = id & 7, loc = id >> 3;      // 8 XCDs x 32 blocks
  const int bm = xcd * 4 + (loc >> 3);        // 4 bm panels per XCD
  const int bn = loc & 7;
  const int w = tid >> 6, l = tid & 63;
  const int wr = w >> 2, wc = w & 3;
  const int lr = l & 15, lq = l >> 4, lx = l & 7;

  const unsigned short* Ablk = A + (size_t)bm * 256 * KAUG;
  const unsigned short* Bblk = B + (size_t)bn * 256 * KAUG;

  const size_t gofs0 = (size_t)(tid >> 3) * KAUG + (size_t)(((tid & 7) ^ ((tid >> 3) & 7)) * 8);
  const size_t gofs1 = (size_t)((tid + 512) >> 3) * KAUG +
                       (size_t)((((tid + 512) & 7) ^ (((tid + 512) >> 3) & 7)) * 8);
  unsigned short* const ldsW = LDS + w * 512;   // wave-uniform dest base

  const int arow = wr * 128 + lr, brow = wc * 64 + lr;
  const int sl0 = (lq ^ lx) * 8, sl1 = ((4 + lq) ^ lx) * 8;

  f32x4 acc[8][4];
  #pragma unroll
  for (int i = 0; i < 8; ++i)
    #pragma unroll
    for (int j = 0; j < 4; ++j) acc[i][j] = f32x4{0.f, 0.f, 0.f, 0.f};
  bf16x8 aF[4][2], bF[4][2];

  auto stage = [&](int isB, int half, int kt) {
    if (kt >= NT64) return;
    const unsigned short* g = (isB ? Bblk : Ablk) + (size_t)(half * 128) * KAUG + (size_t)kt * 64;
    unsigned short* ld = ldsW + isB * 32768 + (kt & 1) * 16384 + half * 8192;
    GLOAD(g + gofs0, ld);
    GLOAD(g + gofs1, ld + 4096);
  };

#define QUAD(MQ, NQ)                                                                     \
  do {                                                                                   \
    _Pragma("unroll") for (int mi_ = 0; mi_ < 4; ++mi_)                                  \
    _Pragma("unroll") for (int ni_ = 0; ni_ < 2; ++ni_)                                  \
    _Pragma("unroll") for (int ks_ = 0; ks_ < 2; ++ks_)                                  \
      acc[(MQ)*4 + mi_][(NQ)*2 + ni_] = __builtin_amdgcn_mfma_f32_16x16x32_bf16(         \
          aF[mi_][ks_], bF[(NQ)*2 + ni_][ks_], acc[(MQ)*4 + mi_][(NQ)*2 + ni_],          \
          0, 0, 0);                                                                      \
  } while (0)

  // prologue: tile0 full + B-halves of tile1; vmcnt(4) -> tile0 resident
  stage(1, 0, 0); stage(1, 1, 0); stage(0, 0, 0); stage(0, 1, 0);
  stage(1, 0, 1); stage(1, 1, 1);
  WAITV4(); PIN(); BAR();

  for (int i = 0; i < NITER; ++i) {
    const int k1 = 2 * i + 1;
    const int a0 = arow * 64,   b0 = 32768 + brow * 64;    // even tile -> buf0
    const int a1 = a0 + 16384,  b1 = b0 + 16384;           // odd tile  -> buf1

    // ---- ph1
    #pragma unroll
    for (int mi = 0; mi < 4; ++mi) {
      aF[mi][0] = *(const bf16x8*)(LDS + a0 + mi * 1024 + sl0);
      aF[mi][1] = *(const bf16x8*)(LDS + a0 + mi * 1024 + sl1);
    }
    #pragma unroll
    for (int ni = 0; ni < 2; ++ni) {
      bF[ni][0] = *(const bf16x8*)(LDS + b0 + ni * 1024 + sl0);
      bF[ni][1] = *(const bf16x8*)(LDS + b0 + ni * 1024 + sl1);
    }
    stage(0, 0, k1);
    PIN(); WAITL(); SB0();
    __builtin_amdgcn_s_setprio(1); QUAD(0, 0); __builtin_amdgcn_s_setprio(0);
    PIN(); BAR();
    // ---- ph2
    #pragma unroll
    for (int ni = 2; ni < 4; ++ni) {
      bF[ni][0] = *(const bf16x8*)(LDS + b0 + ni * 1024 + sl0);
      bF[ni][1] = *(const bf16x8*)(LDS + b0 + ni * 1024 + sl1);
    }
    stage(0, 1, k1);
    PIN(); WAITL(); SB0();
    __builtin_amdgcn_s_setprio(1); QUAD(0, 1); __builtin_amdgcn_s_setprio(0);
    PIN(); BAR();
    // ---- ph3
    #pragma unroll
    for (int mi = 0; mi < 4; ++mi) {
      aF[mi][0] = *(const bf16x8*)(LDS + a0 + (mi + 4) * 1024 + sl0);
      aF[mi][1] = *(const bf16x8*)(LDS + a0 + (mi + 4) * 1024 + sl1);
    }
    stage(1, 0, k1 + 1);
    PIN(); WAITL(); SB0();
    __builtin_amdgcn_s_setprio(1); QUAD(1, 1); __builtin_amdgcn_s_setprio(0);
    PIN(); BAR();
    // ---- ph4
    stage(1, 1, k1 + 1);
    PIN();
    __builtin_amdgcn_s_setprio(1); QUAD(1, 0); __builtin_amdgcn_s_setprio(0);
    PIN();
    if (i == NITER - 1) { WAITV0(); } else { WAITV4(); }
    PIN(); BAR();

    // ---- ph5
    #pragma unroll
    for (int mi = 0; mi < 4; ++mi) {
      aF[mi][0] = *(const bf16x8*)(LDS + a1 + mi * 1024 + sl0);
      aF[mi][1] = *(const bf16x8*)(LDS + a1 + mi * 1024 + sl1);
    }
    #pragma unroll
    for (int ni = 0; ni < 2; ++ni) {
      bF[ni][0] = *(const bf16x8*)(LDS + b1 + ni * 1024 + sl0);
      bF[ni][1] = *(const bf16x8*)(LDS + b1 + ni * 1024 + sl1);
    }
    stage(0, 0, k1 + 1);
    PIN(); WAITL(); SB0();
    __builtin_amdgcn_s_setprio(1); QUAD(0, 0); __builtin_amdgcn_s_setprio(0);
    PIN(); BAR();
    // ---- ph6
    #pragma unroll
    for (int ni = 2; ni < 4; ++ni) {
      bF[ni][0] = *(const bf16x8*)(LDS + b1 + ni * 1024 + sl0);
      bF[ni][1] = *(const bf16x8*)(LDS + b1 + ni * 1024 + sl1);
    }
    stage(0, 1, k1 + 1);
    PIN(); WAITL(); SB0();
    __builtin_amdgcn_s_setprio(1); QUAD(0, 1); __builtin_amdgcn_s_setprio(0);
    PIN(); BAR();
    // ---- ph7
    #pragma unroll
    for (int mi = 0; mi < 4; ++mi) {
      aF[mi][0] = *(const bf16x8*)(LDS + a1 + (mi + 4) * 1024 + sl0);
      aF[mi][1] = *(const bf16x8*)(LDS + a1 + (mi + 4) * 1024 + sl1);
    }
    stage(1, 0, k1 + 2);
    PIN(); WAITL(); SB0();
    __builtin_amdgcn_s_setprio(1); QUAD(1, 1); __builtin_amdgcn_s_setprio(0);
    PIN(); BAR();
    // ---- ph8
    stage(1, 1, k1 + 2);
    PIN();
    __builtin_amdgcn_s_setprio(1); QUAD(1, 0); __builtin_amdgcn_s_setprio(0);
    PIN();
    if (i == NITER - 1) { WAITV0(); } else { WAITV4(); }
    PIN(); BAR();
  }
#undef QUAD

  #pragma unroll
  for (int mi = 0; mi < 8; ++mi)
    #pragma unroll
    for (int ni = 0; ni < 4; ++ni)
      #pragma unroll
      for (int j = 0; j < 4; ++j) {
        int row = bm * 256 + wr * 128 + mi * 16 + lq * 4 + j;
        int col = bn * 256 + wc * 64 + ni * 16 + lr;
        out[(size_t)row * OUT_F + col] = acc[mi][ni][j];
      }
}

extern "C" void kernel_launch(void* const* d_in, const int* in_sizes, int n_in,
                              void* d_out, int out_size, void* d_ws, size_t ws_size,
                              hipStream_t stream) {
  const float* x  = (const float*)d_in[0];
  const float* wt = (const float*)d_in[1];
  const float* la = (const float*)d_in[2];
  const float* lb = (const float*)d_in[3];
  const float* rw = (const float*)d_in[4];
  float* out = (float*)d_out;
  char* ws = (char*)d_ws;

  unsigned short* Ap  = (unsigned short*)ws;                 // bf16 [8192][2176]
  unsigned short* Bp  = (unsigned short*)(ws + 35651584);    // bf16 [2048][2176]
  unsigned short* Ac  = (unsigned short*)(ws + 44564480);    // bf16 [128][2048]
  float*          wsc = (float*)(ws + 45088768);             // f32  [8192][8]

  k_pre<<<1032, 256, 0, stream>>>(x, rw, wt, lb, la, Ap, wsc, Bp, Ac);
  k_lora<<<NTOK / 32, 256, 0, stream>>>(Ap, Ac, wsc, Ap + IN_F);
  k_main<<<256, 512, 0, stream>>>(Ap, Bp, out);
}